// Round 4
// baseline (355.037 us; speedup 1.0000x reference)
//
#include <hip/hip_runtime.h>

// ConvLSTM1D fused scan for MI355X — f32 I/O, bf16 MFMA.
// Round 10: m-split wave doubling. 512-thread blocks (8 waves); wave w owns
// exactly ONE m-slot (rows [16w,16w+16) of the halo window) instead of two.
// Unlike round 7's gate-pair split (which duplicated ds_reads/ax/prefetch and
// regressed), this split duplicates NOTHING: total instructions identical to
// round 9, per-wave work halved, waves/CU 8 -> 16 (4/SIMD) to cover the
// ~55us of dependency/barrier stall (round-9 counters: MFMA 24us + VALU 53us
// busy vs 113us wall). Halo shrink retires whole waves (wave >= nmt).
// Round 9 win kept: B-fragments pre-permuted to bf16 in __device__ tables by
// a prep kernel (coalesced dwordx4 reloads instead of in-loop f2b_rne remat).
// Halo-tile trick: block owns j-range [j0, j0+64); recurrent conv reads h[j+1]
// only, so a right halo that starts at +49 rows and shrinks by 1 per step makes
// every block's 50-step scan fully independent (no grid sync).

#define TT 50
#define LTILE 64
#define ROWS 129   // 64 owned + 49 halo + 1 read-halo row (row 128 stays 0)
#define HSTR 40    // h row stride (shorts); mult of 8 -> 16B-aligned ds_read_b128

typedef __attribute__((ext_vector_type(8))) short short8;
typedef __attribute__((ext_vector_type(4))) float floatx4;

// Prepermuted bf16 weight fragment tables: index [n*64 + lane].
__device__ short8 g_tw0[512];   // rec_kernel tap rows 0..31  (k = q*8+j)
__device__ short8 g_tw1[512];   // rec_kernel tap rows 32..63
__device__ short8 g_txw[512];   // x-conv taps (k rows 0..15) + bias row 16

__device__ __forceinline__ unsigned short f2b_rne(float f) {
  union { float f; unsigned u; } v; v.f = f;
  unsigned r = v.u + 0x7FFFu + ((v.u >> 16) & 1u);
  return (unsigned short)(r >> 16);
}
__device__ __forceinline__ unsigned short f2b_trunc(float f) {
  union { float f; unsigned u; } v; v.f = f;
  return (unsigned short)(v.u >> 16);
}
__device__ __forceinline__ float hsig(float x) {
  return __builtin_amdgcn_fmed3f(__builtin_fmaf(0.2f, x, 0.5f), 0.0f, 1.0f);
}
__device__ __forceinline__ float ftanh(float x) {
  float e = __expf(2.0f * x);
  return 1.0f - 2.0f * __builtin_amdgcn_rcpf(e + 1.0f);
}

// ---- prep: build fragment tables (once) + zero the batch accumulators.
__global__ void prep(const float* __restrict__ ks,
                     const float* __restrict__ rks,
                     const float* __restrict__ bs,
                     float* __restrict__ ws) {
  const int lane = threadIdx.x;        // 0..63
  if (lane < 32) ws[lane] = 0.0f;
  const int q  = lane >> 4;
  const int f0 = lane & 15;
#pragma unroll
  for (int n = 0; n < 8; ++n) {
    // Gate-pair permutation: tile n = 2g+p, col f0  <->  oc = g*32 + 2*f0 + p
    const int oc = (n >> 1) * 32 + 2 * f0 + (n & 1);
    short8 th;
#pragma unroll
    for (int j = 0; j < 8; ++j)
      th[j] = (short)f2b_rne(rks[(q * 8 + j) * 128 + oc]);
    g_tw0[n * 64 + lane] = th;
#pragma unroll
    for (int j = 0; j < 8; ++j)
      th[j] = (short)f2b_rne(rks[(32 + q * 8 + j) * 128 + oc]);
    g_tw1[n * 64 + lane] = th;
    // x-conv B: k rows 0..7 = tap0, 8..15 = tap1 (paired with x_hi),
    // row 16 = bias (ax carries 1.0 there), rows 17..31 = 0.
    short8 tx = {0, 0, 0, 0, 0, 0, 0, 0};
    if (q < 2) {
#pragma unroll
      for (int j = 0; j < 8; ++j)
        tx[j] = (short)f2b_rne(ks[(q * 8 + j) * 128 + oc]);
    } else if (q == 2) {
      tx[0] = (short)f2b_rne(bs[oc]);
    }
    g_txw[n * 64 + lane] = tx;
  }
}

__global__ __launch_bounds__(512, 4)
void convlstm_scan(const float* __restrict__ xs,   // x [32][50][2048][8] f32
                   const float* __restrict__ dws,  // dense_w [32768] f32
                   float* __restrict__ acc_out) {  // [32] f32 accumulators
  __shared__ short hbH[2][ROWS * HSTR];   // h (bf16), double-buffered

  const int tid  = threadIdx.x;
  const int b    = blockIdx.x >> 4;
  const int j0   = (blockIdx.x & 15) * LTILE;
  const int wave = tid >> 6;           // = m-slot owned by this wave
  const int lane = tid & 63;
  const int q    = lane >> 4;
  const int f0   = lane & 15;

  for (int e = tid; e < ROWS * HSTR; e += 512)
    ((int*)hbH)[e] = 0;

  // ---- B fragments: coalesced loads from the prepermuted tables.
  // tile n = 2g+p, col f0  <->  oc = g*32 + 2*f0 + p  => lane f0's two
  // outputs per row are adjacent h-cols 2f0, 2f0+1 (packed b32 store).
  short8 Bwh0[8], Bwh1[8], Bxw[8];
#pragma unroll
  for (int n = 0; n < 8; ++n) {
    Bwh0[n] = g_tw0[n * 64 + lane];
    Bwh1[n] = g_tw1[n * 64 + lane];
    Bxw[n]  = g_txw[n * 64 + lane];
  }

  // ax constant part: lane (q=2, elem 0) = bf16 1.0 (bias marker), else 0.
  short8 axc = {0, 0, 0, 0, 0, 0, 0, 0};
  if (q == 2) axc[0] = (short)0x3F80;

  const floatx4 zero4 = {0.0f, 0.0f, 0.0f, 0.0f};

  float cst[8];   // c-state, MFMA C-layout: [p*4 + r]
#pragma unroll
  for (int i = 0; i < 8; ++i) cst[i] = 0.0f;

  // ---- per-wave fixed row index; initial x prefetch (t=0)
  const int jr = wave * 16 + f0;            // row in window, < 128
  const int jm = min(j0 + jr, 1023);        // clamped global j (halo overhang)
  const float* xbase = xs + (size_t)b * TT * (2048 * 8);
  floatx4 px0 = zero4, px1 = zero4;
  if (q < 2) {                              // only q<2 lanes feed ax
    const float* xp = xbase + (size_t)(2 * jm + q) * 8;
    px0 = *(const floatx4*)xp;
    px1 = *(const floatx4*)(xp + 4);
  }

  const int maxrows = 1024 - j0;
  float part = 0.0f;                        // fused Dense(1) partial
  __syncthreads();

  for (int t = 0; t < TT; ++t) {
    const short* curH = hbH[t & 1];
    short* nxtH = hbH[(t & 1) ^ 1];
    int rows = LTILE + (TT - 1) - t;          // halo shrinks 1/step
    if (rows > maxrows) rows = maxrows;
    const int nmt = (rows + 15) >> 4;         // 4..8 live m-slots
    const int last = (t == TT - 1);

    if (wave < nmt) {                         // wave-uniform; retired waves
      // 1) a-frag LDS reads (max row read = 128 = ROWS-1, stays 0).
      short8 a0h = *(const short8*)&curH[jr * HSTR + q * 8];
      short8 a1h = *(const short8*)&curH[(jr + 1) * HSTR + q * 8];

      // 2) ax (x_hi) from registers prefetched last step.
      // k = q*8+j: q0 -> hi(x[2J][j]), q1 -> hi(x[2J+1][j]), q2 -> bias.
      short8 ax = axc;
      if (q < 2) {
#pragma unroll
        for (int jj = 0; jj < 4; ++jj) ax[jj] = (short)f2b_trunc(px0[jj]);
#pragma unroll
        for (int jj = 0; jj < 4; ++jj) ax[4 + jj] = (short)f2b_trunc(px1[jj]);
      }

      // 3) next-step x prefetch (longest latency, overlaps MFMA below).
      const int tn = last ? t : t + 1;
      if (q < 2) {
        const float* xp = xbase + ((size_t)tn * 2048 + (size_t)(2 * jm + q)) * 8;
        px0 = *(const floatx4*)xp;
        px1 = *(const floatx4*)(xp + 4);
      }

      // 4) MFMA: x-conv first (register operands, C=0) while ds_reads land.
      floatx4 acc[8];
#pragma unroll
      for (int n = 0; n < 8; ++n)
        acc[n] = __builtin_amdgcn_mfma_f32_16x16x32_bf16(ax, Bxw[n], zero4, 0, 0, 0);
#pragma unroll
      for (int n = 0; n < 8; ++n)
        acc[n] = __builtin_amdgcn_mfma_f32_16x16x32_bf16(a0h, Bwh0[n], acc[n], 0, 0, 0);
#pragma unroll
      for (int n = 0; n < 8; ++n)
        acc[n] = __builtin_amdgcn_mfma_f32_16x16x32_bf16(a1h, Bwh1[n], acc[n], 0, 0, 0);

      // 5) Pointwise LSTM. D[row = q*4+r][tile n, col f0 -> h-col 2f0+(n&1)].
      // Gate g in tiles {2g, 2g+1}: zi=acc[0+p], zf=acc[2+p], zc=acc[4+p],
      // zo=acc[6+p] give h-col 2f0+p.
      const int jw = wave * 16 + q * 4;
#pragma unroll
      for (int r = 0; r < 4; ++r) {
        float hv2[2];
#pragma unroll
        for (int p = 0; p < 2; ++p) {
          float zi = acc[0 + p][r], zf = acc[2 + p][r];
          float zc = acc[4 + p][r], zo = acc[6 + p][r];
          float ig = hsig(zi), fg = hsig(zf), og = hsig(zo);
          float cs = cst[p * 4 + r];
          float cn = __builtin_fmaf(fg, cs, ig * ftanh(zc));
          cst[p * 4 + r] = cn;
          hv2[p] = og * ftanh(cn);
        }
        if (!last) {
          unsigned pk;
          asm("v_cvt_pk_bf16_f32 %0, %1, %2"
              : "=v"(pk) : "v"(hv2[0]), "v"(hv2[1]));
          *(unsigned*)&nxtH[(jw + r) * HSTR + 2 * f0] = pk;
        } else {
          // t=49: nmt=4 -> waves 0..3; rows jw+r cover exactly [0,64).
          const int di = (j0 + jw + r) * 32 + 2 * f0;
          part = __builtin_fmaf(hv2[0], dws[di],
                 __builtin_fmaf(hv2[1], dws[di + 1], part));
        }
      }
    }
    __syncthreads();
  }

  // ---- reduce fused-dense partials (only waves 0..3 hold nonzero part)
#pragma unroll
  for (int off = 32; off > 0; off >>= 1) part += __shfl_down(part, off);
  if (lane == 0 && wave < 4) atomicAdd(&acc_out[b], part);
}

__global__ void finalize(const float* __restrict__ ws,
                         const float* __restrict__ db,
                         float* __restrict__ out) {
  int i = threadIdx.x;
  if (i < 32) out[i] = ws[i] + db[0];
}

extern "C" void kernel_launch(void* const* d_in, const int* in_sizes, int n_in,
                              void* d_out, int out_size, void* d_ws, size_t ws_size,
                              hipStream_t stream) {
  const float* x  = (const float*)d_in[0];
  const float* k  = (const float*)d_in[1];
  const float* rk = (const float*)d_in[2];
  const float* bi = (const float*)d_in[3];
  const float* dw = (const float*)d_in[4];
  const float* db = (const float*)d_in[5];
  float* ws = (float*)d_ws;
  float* out = (float*)d_out;

  hipLaunchKernelGGL(prep, dim3(1), dim3(64), 0, stream, k, rk, bi, ws);
  hipLaunchKernelGGL(convlstm_scan, dim3(512), dim3(512), 0, stream,
                     x, dw, ws);
  hipLaunchKernelGGL(finalize, dim3(1), dim3(64), 0, stream, ws, db, out);
}

// Round 5
// 244.193 us; speedup vs baseline: 1.4539x; 1.4539x over previous
//
#include <hip/hip_runtime.h>

// ConvLSTM1D fused scan for MI355X — f32 I/O, bf16 MFMA.
// Round 11: occupancy push WITHOUT spill risk. Round 10's launch_bounds cap
// spilled the 24 B-fragments to scratch (WRITE_SIZE 64KB->37MB, FETCH +167MB,
// 2.1x regression). Fix: stage the three prepermuted weight tables into LDS
// (24 KB/block, contiguous b128 reads, conflict-free) so a register cap
// degrades into cheap in-loop ds_read_b128 instead of scratch. Then
// __launch_bounds__(256,3) (cap ~170 regs) + LDS 45.2 KB/block -> 3 blocks/CU
// = 12 waves/CU (was 8) to cover the ~36us of exposed stall in round 9
// (MFMA busy 24us + VALU busy 53us vs 113us wall).
// Round 9/6 wins kept: prep kernel builds gate-pair-permuted bf16 fragment
// tables once; v_cvt_pk_bf16_f32 h-store; fused Dense(1) epilogue.
// Halo-tile trick: block owns j-range [j0, j0+64); recurrent conv reads h[j+1]
// only, so a right halo that starts at +49 rows and shrinks by 1 per step makes
// every block's 50-step scan fully independent (no grid sync).

#define TT 50
#define LTILE 64
#define ROWS 129   // 64 owned + 49 halo + 1 read-halo row (row 128 stays 0)
#define HSTR 40    // h row stride (shorts); mult of 8 -> 16B-aligned ds_read_b128

typedef __attribute__((ext_vector_type(8))) short short8;
typedef __attribute__((ext_vector_type(4))) float floatx4;

// Prepermuted bf16 weight fragment tables: index [n*64 + lane].
__device__ short8 g_tw0[512];   // rec_kernel tap rows 0..31  (k = q*8+j)
__device__ short8 g_tw1[512];   // rec_kernel tap rows 32..63
__device__ short8 g_txw[512];   // x-conv taps (k rows 0..15) + bias row 16

__device__ __forceinline__ unsigned short f2b_rne(float f) {
  union { float f; unsigned u; } v; v.f = f;
  unsigned r = v.u + 0x7FFFu + ((v.u >> 16) & 1u);
  return (unsigned short)(r >> 16);
}
__device__ __forceinline__ unsigned short f2b_trunc(float f) {
  union { float f; unsigned u; } v; v.f = f;
  return (unsigned short)(v.u >> 16);
}
__device__ __forceinline__ float hsig(float x) {
  return __builtin_amdgcn_fmed3f(__builtin_fmaf(0.2f, x, 0.5f), 0.0f, 1.0f);
}
__device__ __forceinline__ float ftanh(float x) {
  float e = __expf(2.0f * x);
  return 1.0f - 2.0f * __builtin_amdgcn_rcpf(e + 1.0f);
}

// ---- prep: build fragment tables (once) + zero the batch accumulators.
__global__ void prep(const float* __restrict__ ks,
                     const float* __restrict__ rks,
                     const float* __restrict__ bs,
                     float* __restrict__ ws) {
  const int lane = threadIdx.x;        // 0..63
  if (lane < 32) ws[lane] = 0.0f;
  const int q  = lane >> 4;
  const int f0 = lane & 15;
#pragma unroll
  for (int n = 0; n < 8; ++n) {
    // Gate-pair permutation: tile n = 2g+p, col f0  <->  oc = g*32 + 2*f0 + p
    const int oc = (n >> 1) * 32 + 2 * f0 + (n & 1);
    short8 th;
#pragma unroll
    for (int j = 0; j < 8; ++j)
      th[j] = (short)f2b_rne(rks[(q * 8 + j) * 128 + oc]);
    g_tw0[n * 64 + lane] = th;
#pragma unroll
    for (int j = 0; j < 8; ++j)
      th[j] = (short)f2b_rne(rks[(32 + q * 8 + j) * 128 + oc]);
    g_tw1[n * 64 + lane] = th;
    // x-conv B: k rows 0..7 = tap0, 8..15 = tap1 (paired with x_hi),
    // row 16 = bias (ax carries 1.0 there), rows 17..31 = 0.
    short8 tx = {0, 0, 0, 0, 0, 0, 0, 0};
    if (q < 2) {
#pragma unroll
      for (int j = 0; j < 8; ++j)
        tx[j] = (short)f2b_rne(ks[(q * 8 + j) * 128 + oc]);
    } else if (q == 2) {
      tx[0] = (short)f2b_rne(bs[oc]);
    }
    g_txw[n * 64 + lane] = tx;
  }
}

__global__ __launch_bounds__(256, 3)
void convlstm_scan(const float* __restrict__ xs,   // x [32][50][2048][8] f32
                   const float* __restrict__ dws,  // dense_w [32768] f32
                   float* __restrict__ acc_out) {  // [32] f32 accumulators
  __shared__ short hbH[2][ROWS * HSTR];   // h (bf16), double-buffered, 20.6 KB
  __shared__ short8 sTw0[512];            // LDS copies of the weight tables
  __shared__ short8 sTw1[512];            // (24 KB total; reg-cap overflow
  __shared__ short8 sTxw[512];            //  becomes ds_read, NOT scratch)

  const int tid  = threadIdx.x;
  const int b    = blockIdx.x >> 4;
  const int j0   = (blockIdx.x & 15) * LTILE;
  const int wave = tid >> 6;
  const int lane = tid & 63;
  const int q    = lane >> 4;
  const int f0   = lane & 15;

  for (int e = tid; e < ROWS * HSTR; e += 256)
    ((int*)hbH)[e] = 0;
  // stage weight tables global -> LDS (once per block; 24 KB)
  for (int e = tid; e < 512; e += 256) {
    sTw0[e] = g_tw0[e];
    sTw1[e] = g_tw1[e];
    sTxw[e] = g_txw[e];
  }

  // ax constant part: lane (q=2, elem 0) = bf16 1.0 (bias marker), else 0.
  short8 axc = {0, 0, 0, 0, 0, 0, 0, 0};
  if (q == 2) axc[0] = (short)0x3F80;

  const floatx4 zero4 = {0.0f, 0.0f, 0.0f, 0.0f};

  float cst[2][8];   // c-state, MFMA C-layout: [m-slot][p*4 + r]
#pragma unroll
  for (int s = 0; s < 2; ++s)
#pragma unroll
    for (int i = 0; i < 8; ++i) cst[s][i] = 0.0f;

  // ---- initial x prefetch (t=0) for both slots (only q<2 feeds ax)
  floatx4 px0[2], px1[2];
#pragma unroll
  for (int s = 0; s < 2; ++s) {
    px0[s] = zero4; px1[s] = zero4;
    const int jr = (wave + 4 * s) * 16 + f0;
    const int jm = min(j0 + jr, 1023);
    if (q < 2) {
      const float* xp = xs + (size_t)b * TT * (2048 * 8) +
                        (size_t)(2 * jm + q) * 8;
      px0[s] = *(const floatx4*)xp;
      px1[s] = *(const floatx4*)(xp + 4);
    }
  }

  const int maxrows = 1024 - j0;
  float part = 0.0f;                        // fused Dense(1) partial
  __syncthreads();                          // covers hbH init + table staging

  for (int t = 0; t < TT; ++t) {
    const short* curH = hbH[t & 1];
    short* nxtH = hbH[(t & 1) ^ 1];
    int rows = LTILE + (TT - 1) - t;          // halo shrinks 1/step
    if (rows > maxrows) rows = maxrows;
    const int nmt = (rows + 15) >> 4;         // 4..8; slot0 (m=wave) always live
    const int act1 = (wave + 4) < nmt;        // wave-uniform slot1 guard
    const int last = (t == TT - 1);
    const int tn = last ? t : t + 1;
    const float* xnext = xs + ((size_t)(b * TT + tn)) * (2048 * 8);

    // 1) Front-load a-frag LDS reads (both slots; max row read = 128 = ROWS-1).
    short8 a0h[2], a1h[2];
#pragma unroll
    for (int s = 0; s < 2; ++s) {
      const int jr = (wave + 4 * s) * 16 + f0;
      a0h[s] = *(const short8*)&curH[jr * HSTR + q * 8];
      a1h[s] = *(const short8*)&curH[(jr + 1) * HSTR + q * 8];
    }

    // 2) Build ax (x_hi) from registers prefetched last step.
    // k = q*8+j: q0 -> hi(x[2J][j]), q1 -> hi(x[2J+1][j]), q2 -> bias marker.
    short8 ax[2];
#pragma unroll
    for (int s = 0; s < 2; ++s) {
      ax[s] = axc;
      if (q < 2) {
        floatx4 x0 = px0[s], x1 = px1[s];
#pragma unroll
        for (int jj = 0; jj < 4; ++jj) ax[s][jj] = (short)f2b_trunc(x0[jj]);
#pragma unroll
        for (int jj = 0; jj < 4; ++jj) ax[s][4 + jj] = (short)f2b_trunc(x1[jj]);
      }
    }

    // 3) Issue next-step x prefetch (longest latency, overlaps MFMA below).
#pragma unroll
    for (int s = 0; s < 2; ++s) {
      const int jr = (wave + 4 * s) * 16 + f0;
      const int jm = min(j0 + jr, 1023);
      if (q < 2) {
        const float* xp = xnext + (size_t)(2 * jm + q) * 8;
        px0[s] = *(const floatx4*)xp;
        px1[s] = *(const floatx4*)(xp + 4);
      }
    }

    // 4) Per-slot MFMA + pointwise. B-fragments stream from LDS; whatever
    //    the allocator can hoist under the (256,3) cap stays in regs, the
    //    rest re-reads LDS (cheap, broadcastable) instead of scratch.
#pragma unroll
    for (int s = 0; s < 2; ++s) {
      if (s == 1 && !act1) continue;
      const int m = wave + 4 * s;

      floatx4 acc[8];
#pragma unroll
      for (int n = 0; n < 8; ++n) {
        short8 bx = sTxw[n * 64 + lane];
        acc[n] = __builtin_amdgcn_mfma_f32_16x16x32_bf16(ax[s], bx, zero4, 0, 0, 0);
      }
#pragma unroll
      for (int n = 0; n < 8; ++n) {
        short8 bw = sTw0[n * 64 + lane];
        acc[n] = __builtin_amdgcn_mfma_f32_16x16x32_bf16(a0h[s], bw, acc[n], 0, 0, 0);
      }
#pragma unroll
      for (int n = 0; n < 8; ++n) {
        short8 bw = sTw1[n * 64 + lane];
        acc[n] = __builtin_amdgcn_mfma_f32_16x16x32_bf16(a1h[s], bw, acc[n], 0, 0, 0);
      }

      // Pointwise LSTM. D[m-row = q*4+r][tile n, col f0 -> h-col 2f0 + (n&1)].
      // Gate g in tiles {2g, 2g+1}: zi=acc[0+p], zf=acc[2+p], zc=acc[4+p],
      // zo=acc[6+p] give h-col 2f0+p.
      const int jw = m * 16 + q * 4;
#pragma unroll
      for (int r = 0; r < 4; ++r) {
        float hv2[2];
#pragma unroll
        for (int p = 0; p < 2; ++p) {
          float zi = acc[0 + p][r], zf = acc[2 + p][r];
          float zc = acc[4 + p][r], zo = acc[6 + p][r];
          float ig = hsig(zi), fg = hsig(zf), og = hsig(zo);
          float cs = cst[s][p * 4 + r];
          float cn = __builtin_fmaf(fg, cs, ig * ftanh(zc));
          cst[s][p * 4 + r] = cn;
          hv2[p] = og * ftanh(cn);
        }
        if (!last) {
          unsigned pk;
          asm("v_cvt_pk_bf16_f32 %0, %1, %2"
              : "=v"(pk) : "v"(hv2[0]), "v"(hv2[1]));
          *(unsigned*)&nxtH[(jw + r) * HSTR + 2 * f0] = pk;
        } else {
          // t=49: nmt=4, s=0 only; rows jw+r cover exactly [0,64).
          const int di = (j0 + jw + r) * 32 + 2 * f0;
          part = __builtin_fmaf(hv2[0], dws[di],
                 __builtin_fmaf(hv2[1], dws[di + 1], part));
        }
      }
    }
    __syncthreads();
  }

  // ---- reduce fused-dense partials
#pragma unroll
  for (int off = 32; off > 0; off >>= 1) part += __shfl_down(part, off);
  if (lane == 0) atomicAdd(&acc_out[b], part);
}

__global__ void finalize(const float* __restrict__ ws,
                         const float* __restrict__ db,
                         float* __restrict__ out) {
  int i = threadIdx.x;
  if (i < 32) out[i] = ws[i] + db[0];
}

extern "C" void kernel_launch(void* const* d_in, const int* in_sizes, int n_in,
                              void* d_out, int out_size, void* d_ws, size_t ws_size,
                              hipStream_t stream) {
  const float* x  = (const float*)d_in[0];
  const float* k  = (const float*)d_in[1];
  const float* rk = (const float*)d_in[2];
  const float* bi = (const float*)d_in[3];
  const float* dw = (const float*)d_in[4];
  const float* db = (const float*)d_in[5];
  float* ws = (float*)d_ws;
  float* out = (float*)d_out;

  hipLaunchKernelGGL(prep, dim3(1), dim3(64), 0, stream, k, rk, bi, ws);
  hipLaunchKernelGGL(convlstm_scan, dim3(512), dim3(256), 0, stream,
                     x, dw, ws);
  hipLaunchKernelGGL(finalize, dim3(1), dim3(64), 0, stream, ws, db, out);
}